// Round 1
// baseline (565.571 us; speedup 1.0000x reference)
//
#include <hip/hip_runtime.h>
#include <hip/hip_bf16.h>

#define N_FEAT 256   // IN_FEAT == H*F == 256
#define NHEAD 4
#define FDIM 64
#define ALPHA 0.2f

// ---------------- GEMM: h = x @ W  (M x 256) * (256 x 256) ----------------
__global__ __launch_bounds__(256) void gemm_kernel(const float* __restrict__ x,
                                                   const float* __restrict__ W,
                                                   float* __restrict__ h, int M) {
    __shared__ float As[16][64];  // As[k][m]
    __shared__ float Bs[16][64];  // Bs[k][n]
    const int tid = threadIdx.x;
    const int tx = tid & 15, ty = tid >> 4;
    const int row0 = blockIdx.x * 64;
    const int col0 = blockIdx.y * 64;

    float acc[4][4] = {};

    const int lr = tid >> 2;          // 0..63 row for A load
    const int lk = (tid & 3) * 4;     // k group of 4
    const int bk = tid >> 4;          // 0..15 k for B load
    const int bn = (tid & 15) * 4;    // n group of 4

    for (int k0 = 0; k0 < 256; k0 += 16) {
        float4 xa = make_float4(0.f, 0.f, 0.f, 0.f);
        if (row0 + lr < M)
            xa = *(const float4*)&x[(size_t)(row0 + lr) * N_FEAT + k0 + lk];
        As[lk + 0][lr] = xa.x;
        As[lk + 1][lr] = xa.y;
        As[lk + 2][lr] = xa.z;
        As[lk + 3][lr] = xa.w;
        float4 wb = *(const float4*)&W[(size_t)(k0 + bk) * N_FEAT + col0 + bn];
        *(float4*)&Bs[bk][bn] = wb;
        __syncthreads();
#pragma unroll
        for (int k = 0; k < 16; ++k) {
            float4 a = *(float4*)&As[k][ty * 4];
            float4 b = *(float4*)&Bs[k][tx * 4];
            acc[0][0] += a.x * b.x; acc[0][1] += a.x * b.y; acc[0][2] += a.x * b.z; acc[0][3] += a.x * b.w;
            acc[1][0] += a.y * b.x; acc[1][1] += a.y * b.y; acc[1][2] += a.y * b.z; acc[1][3] += a.y * b.w;
            acc[2][0] += a.z * b.x; acc[2][1] += a.z * b.y; acc[2][2] += a.z * b.z; acc[2][3] += a.z * b.w;
            acc[3][0] += a.w * b.x; acc[3][1] += a.w * b.y; acc[3][2] += a.w * b.z; acc[3][3] += a.w * b.w;
        }
        __syncthreads();
    }
#pragma unroll
    for (int i = 0; i < 4; ++i) {
        int r = row0 + ty * 4 + i;
        if (r < M) {
            float4 v = make_float4(acc[i][0], acc[i][1], acc[i][2], acc[i][3]);
            *(float4*)&h[(size_t)r * N_FEAT + col0 + tx * 4] = v;
        }
    }
}

// ---------------- h_l / h_r: per-node, per-head dot with a_l / a_r ----------------
__global__ __launch_bounds__(256) void hlr_kernel(const float* __restrict__ h,
                                                  const float* __restrict__ a_l,
                                                  const float* __restrict__ a_r,
                                                  float* __restrict__ h_l,
                                                  float* __restrict__ h_r, int N) {
    int node = blockIdx.x;
    if (node >= N) return;
    int wave = threadIdx.x >> 6;
    int lane = threadIdx.x & 63;
    float hv = h[(size_t)node * N_FEAT + wave * FDIM + lane];
    float vl = hv * a_l[wave * FDIM + lane];
    float vr = hv * a_r[wave * FDIM + lane];
#pragma unroll
    for (int off = 32; off > 0; off >>= 1) {
        vl += __shfl_down(vl, off);
        vr += __shfl_down(vr, off);
    }
    if (lane == 0) {
        h_l[node * NHEAD + wave] = vl;
        h_r[node * NHEAD + wave] = vr;
    }
}

// ---------------- CSR build ----------------
__global__ void hist_kernel(const int* __restrict__ row, int* __restrict__ deg, int E) {
    int e = blockIdx.x * blockDim.x + threadIdx.x;
    if (e < E) atomicAdd(&deg[row[e]], 1);
}

__global__ __launch_bounds__(1024) void scan_kernel(const int* __restrict__ deg,
                                                    int* __restrict__ row_ptr, int n) {
    __shared__ int sm[1024];
    __shared__ int carry_s;
    int t = threadIdx.x;
    if (t == 0) { carry_s = 0; row_ptr[0] = 0; }
    __syncthreads();
    for (int base = 0; base < n; base += 1024) {
        int idx = base + t;
        int v = (idx < n) ? deg[idx] : 0;
        sm[t] = v;
        __syncthreads();
        for (int off = 1; off < 1024; off <<= 1) {
            int tv = (t >= off) ? sm[t - off] : 0;
            __syncthreads();
            sm[t] += tv;
            __syncthreads();
        }
        int incl = sm[t];
        int carry = carry_s;
        if (idx < n) row_ptr[idx + 1] = carry + incl;
        __syncthreads();
        if (t == 1023) carry_s = carry + incl;
        __syncthreads();
    }
}

__global__ void scatter_kernel(const int* __restrict__ row, const int* __restrict__ col,
                               const int* __restrict__ row_ptr, int* __restrict__ fill,
                               int* __restrict__ perm_col, int E) {
    int e = blockIdx.x * blockDim.x + threadIdx.x;
    if (e < E) {
        int r = row[e];
        int pos = row_ptr[r] + atomicAdd(&fill[r], 1);
        perm_col[pos] = col[e];
    }
}

// ---------------- Aggregate: online softmax + weighted gather ----------------
__global__ __launch_bounds__(256) void aggregate_kernel(const float* __restrict__ h,
                                                        const float* __restrict__ h_l,
                                                        const float* __restrict__ h_r,
                                                        const int* __restrict__ row_ptr,
                                                        const int* __restrict__ perm_col,
                                                        float* __restrict__ out, int N) {
    int node = blockIdx.x;
    if (node >= N) return;
    int wave = threadIdx.x >> 6;  // head
    int lane = threadIdx.x & 63;  // feature
    int start = row_ptr[node];
    int end = row_ptr[node + 1];
    float hl = h_l[node * NHEAD + wave];
    float m = -1e30f, s = 0.f, acc = 0.f;
    for (int j = start; j < end; ++j) {
        int c = perm_col[j];
        float e = hl + h_r[c * NHEAD + wave];
        e = (e > 0.f) ? e : ALPHA * e;
        float nm = fmaxf(m, e);
        float scale = __expf(m - nm);
        float p = __expf(e - nm);
        float hv = h[(size_t)c * N_FEAT + wave * FDIM + lane];
        s = s * scale + p;
        acc = acc * scale + p * hv;
        m = nm;
    }
    out[(size_t)node * N_FEAT + wave * FDIM + lane] = acc / fmaxf(s, 1e-16f);
}

extern "C" void kernel_launch(void* const* d_in, const int* in_sizes, int n_in,
                              void* d_out, int out_size, void* d_ws, size_t ws_size,
                              hipStream_t stream) {
    const float* x = (const float*)d_in[0];
    const int* edge = (const int*)d_in[1];
    const float* W = (const float*)d_in[2];
    const float* a_l = (const float*)d_in[3];
    const float* a_r = (const float*)d_in[4];
    float* out = (float*)d_out;

    const int N = in_sizes[0] / N_FEAT;   // 50000
    const int E = in_sizes[1] / 2;        // 800000
    const int* row = edge;
    const int* col = edge + E;

    // workspace layout (16B aligned chunks)
    char* p = (char*)d_ws;
    float* h = (float*)p;       p += (size_t)N * N_FEAT * sizeof(float);
    float* h_l = (float*)p;     p += (size_t)N * NHEAD * sizeof(float);
    float* h_r = (float*)p;     p += (size_t)N * NHEAD * sizeof(float);
    int* deg = (int*)p;         p += (size_t)N * sizeof(int);
    int* row_ptr = (int*)p;     p += (size_t)(N + 4) * sizeof(int);
    int* fill = (int*)p;        p += (size_t)N * sizeof(int);
    int* perm_col = (int*)p;    p += (size_t)E * sizeof(int);

    hipMemsetAsync(deg, 0, (size_t)N * sizeof(int), stream);
    hipMemsetAsync(fill, 0, (size_t)N * sizeof(int), stream);

    dim3 ggrid((N + 63) / 64, N_FEAT / 64);
    gemm_kernel<<<ggrid, 256, 0, stream>>>(x, W, h, N);

    hlr_kernel<<<N, 256, 0, stream>>>(h, a_l, a_r, h_l, h_r, N);

    hist_kernel<<<(E + 255) / 256, 256, 0, stream>>>(row, deg, E);
    scan_kernel<<<1, 1024, 0, stream>>>(deg, row_ptr, N);
    scatter_kernel<<<(E + 255) / 256, 256, 0, stream>>>(row, col, row_ptr, fill, perm_col, E);

    aggregate_kernel<<<N, 256, 0, stream>>>(h, h_l, h_r, row_ptr, perm_col, out, N);
}